// Round 2
// baseline (1427.948 us; speedup 1.0000x reference)
//
#include <hip/hip_runtime.h>
#include <hip/hip_bf16.h>

#define GN 16384
#define GD 128
#define KSPLIT 4
#define KBLK (GN / KSPLIT)          // 4096 k per block
#define CHUNK_K 128                 // k per staged LDS chunk
#define NCHUNK (KBLK / CHUNK_K)     // 32 chunks
#define CHUNK_SHORTS (GD * CHUNK_K) // 16384 shorts = 32 KB
#define OUT_ELEMS (GN * GD)         // 2097152

typedef __attribute__((ext_vector_type(8))) short short8;
typedef __attribute__((ext_vector_type(4))) float floatx4;
typedef __attribute__((ext_vector_type(4))) int intx4;

static __device__ __forceinline__ unsigned short f32_to_bf16(float f) {
  unsigned u = __builtin_bit_cast(unsigned, f);
  unsigned r = u + 0x7FFFu + ((u >> 16) & 1u);  // RNE (inputs finite/normal)
  return (unsigned short)(r >> 16);
}

// Kernel 1: xT[d][j] <- bf16(x[j][d])  (4 MiB, stays L2/L3-resident for gemm staging)
__global__ __launch_bounds__(256) void prep_kernel(const float* __restrict__ x,
                                                   unsigned short* __restrict__ xT) {
  __shared__ unsigned short t[GD][66];  // +2 pad: 4B-aligned, conflict-free
  const int tid = threadIdx.x;
  const int j0 = blockIdx.x * 64;
  for (int i = tid; i < 64 * GD; i += 256) {
    int j = i >> 7, d = i & (GD - 1);
    t[d][j] = f32_to_bf16(x[(size_t)(j0 + j) * GD + d]);
  }
  __syncthreads();
  for (int i = tid; i < GD * 32; i += 256) {
    int d = i >> 5, jp = i & 31;
    unsigned lo = t[d][2 * jp], hi = t[d][2 * jp + 1];
    *reinterpret_cast<unsigned*>(xT + (size_t)d * GN + j0 + 2 * jp) = lo | (hi << 16);
  }
}

// Kernel 2: partial[by] rows = adj[rows, kslice] @ x[kslice]   (bf16 MFMA, fp32 acc)
// 256 thr / 4 waves; BM=128 x BN=128(full D); chunked double-buffered B staging.
// B LDS layout: row n (0..127) of CHUNK_K k's, 16B granules XOR-swizzled: granule g
// of row n stored at slot g^(n&15)  ->  fragment ds_read_b128 is 2-way (free).
__global__ __launch_bounds__(256, 2) void gemm_kernel(const int* __restrict__ adj,
                                                      const unsigned short* __restrict__ xT,
                                                      float* __restrict__ partials) {
  __shared__ unsigned short bbuf[2][CHUNK_SHORTS];  // 2 x 32 KB
  const int tid = threadIdx.x;
  const int wave = tid >> 6;
  const int lane = tid & 63;
  const int q = lane >> 4;   // 0..3
  const int m = lane & 15;   // 0..15
  const int rbase = blockIdx.x * 128 + wave * 32;
  const int kbase = blockIdx.y * KBLK;

  // ---- staging descriptors: 8 x 16B granules per thread, lane-contiguous LDS dest
  const unsigned short* gptr[8];
  unsigned short* lptr[8];
#pragma unroll
  for (int p = 0; p < 8; ++p) {
    int s = tid + 256 * p;            // granule slot 0..2047
    int n = s >> 4;                   // B row (= d index)
    int gsrc = (s & 15) ^ (n & 15);   // XOR swizzle (involution)
    gptr[p] = xT + (size_t)n * GN + kbase + gsrc * 8;
    lptr[p] = &bbuf[0][0] + (size_t)s * 8;
  }

#define STAGE(bufsel, koff)                                                              \
  do {                                                                                   \
    _Pragma("unroll") for (int p = 0; p < 8; ++p) {                                      \
      __builtin_amdgcn_global_load_lds(                                                  \
          (const __attribute__((address_space(1))) unsigned int*)(gptr[p] + (koff)),     \
          (__attribute__((address_space(3))) unsigned int*)(lptr[p] +                    \
                                                           (bufsel) * CHUNK_SHORTS),     \
          16, 0, 0);                                                                     \
    }                                                                                    \
  } while (0)

  const int* a0 = adj + (size_t)(rbase + m) * GN + kbase + q * 8;
  const int* a1 = adj + (size_t)(rbase + 16 + m) * GN + kbase + q * 8;

  floatx4 acc[2][8];
#pragma unroll
  for (int t = 0; t < 2; ++t)
#pragma unroll
    for (int c = 0; c < 8; ++c) acc[t][c] = (floatx4){0.f, 0.f, 0.f, 0.f};

  STAGE(0, 0);  // chunk 0 -> buf 0

  int buf = 0;
  for (int c = 0; c < NCHUNK; ++c) {
    __syncthreads();  // drains: staging of current chunk + last chunk's adj loads
    if (c < NCHUNK - 1) STAGE(buf ^ 1, (c + 1) * CHUNK_K);

#pragma unroll
    for (int kk = 0; kk < 4; ++kk) {
      const int koff = c * CHUNK_K + kk * 32;
      intx4 r0 = __builtin_nontemporal_load((const intx4*)(a0 + koff));
      intx4 r1 = __builtin_nontemporal_load((const intx4*)(a0 + koff + 4));
      intx4 r2 = __builtin_nontemporal_load((const intx4*)(a1 + koff));
      intx4 r3 = __builtin_nontemporal_load((const intx4*)(a1 + koff + 4));

      // B fragments: lane (q,m) of col-tile cc reads row n=cc*16+m, granule (4kk+q)^m
      short8 bf[8];
      const unsigned short* bb = &bbuf[buf][0];
      const int gsw = ((4 * kk + q) ^ m) * 8;
#pragma unroll
      for (int cc = 0; cc < 8; ++cc)
        bf[cc] = *(const short8*)(bb + (cc * 16 + m) * CHUNK_K + gsw);

      // adj int 0/1 -> bf16 0x0000/0x3F80, two elems per dword
      intx4 p0, p1;
      p0.x = (r0.x | (r0.y << 16)) * 0x3F80;
      p0.y = (r0.z | (r0.w << 16)) * 0x3F80;
      p0.z = (r1.x | (r1.y << 16)) * 0x3F80;
      p0.w = (r1.z | (r1.w << 16)) * 0x3F80;
      p1.x = (r2.x | (r2.y << 16)) * 0x3F80;
      p1.y = (r2.z | (r2.w << 16)) * 0x3F80;
      p1.z = (r3.x | (r3.y << 16)) * 0x3F80;
      p1.w = (r3.z | (r3.w << 16)) * 0x3F80;
      short8 af0 = __builtin_bit_cast(short8, p0);
      short8 af1 = __builtin_bit_cast(short8, p1);

#pragma unroll
      for (int cc = 0; cc < 8; ++cc) {
        acc[0][cc] = __builtin_amdgcn_mfma_f32_16x16x32_bf16(af0, bf[cc], acc[0][cc], 0, 0, 0);
        acc[1][cc] = __builtin_amdgcn_mfma_f32_16x16x32_bf16(af1, bf[cc], acc[1][cc], 0, 0, 0);
      }
    }
    buf ^= 1;
  }

  // Epilogue: plain stores to this ksplit's partial buffer (no atomics).
  // C/D layout: col=lane&15, row=q*4+reg.
  float* pp = partials + (size_t)blockIdx.y * OUT_ELEMS + (size_t)rbase * GD;
#pragma unroll
  for (int t = 0; t < 2; ++t)
#pragma unroll
    for (int cc = 0; cc < 8; ++cc)
#pragma unroll
      for (int r = 0; r < 4; ++r) {
        int row = t * 16 + q * 4 + r;
        int col = cc * 16 + m;
        pp[(size_t)row * GD + col] = acc[t][cc][r];
      }
}

// Kernel 3: out = x + sum of 4 partials (also un-poisons d_out)
__global__ __launch_bounds__(256) void reduce_kernel(const float* __restrict__ x,
                                                     const float* __restrict__ partials,
                                                     float* __restrict__ out) {
  size_t i = ((size_t)blockIdx.x * 256 + threadIdx.x) * 4;
  floatx4 v = *(const floatx4*)(x + i);
  v += *(const floatx4*)(partials + 0 * (size_t)OUT_ELEMS + i);
  v += *(const floatx4*)(partials + 1 * (size_t)OUT_ELEMS + i);
  v += *(const floatx4*)(partials + 2 * (size_t)OUT_ELEMS + i);
  v += *(const floatx4*)(partials + 3 * (size_t)OUT_ELEMS + i);
  *(floatx4*)(out + i) = v;
}

extern "C" void kernel_launch(void* const* d_in, const int* in_sizes, int n_in,
                              void* d_out, int out_size, void* d_ws, size_t ws_size,
                              hipStream_t stream) {
  const float* x = (const float*)d_in[0];
  const int* adj = (const int*)d_in[1];
  float* out = (float*)d_out;
  unsigned short* xT = (unsigned short*)d_ws;                 // 4 MiB
  float* partials = (float*)((char*)d_ws + (size_t)GN * GD * 2);  // 4 x 8 MiB

  prep_kernel<<<GN / 64, 256, 0, stream>>>(x, xT);
  gemm_kernel<<<dim3(GN / 128, KSPLIT), 256, 0, stream>>>(adj, xT, partials);
  reduce_kernel<<<OUT_ELEMS / 4 / 256, 256, 0, stream>>>(x, partials, out);
}